// Round 1
// baseline (107.487 us; speedup 1.0000x reference)
//
#include <hip/hip_runtime.h>

// EncoderBlock: gather(x, idx) -> per-o GEMM (512x128 @ K=512) + bias
//               -> BatchNorm over B=512 -> SiLU.
// K1: bf16 MFMA GEMM (fp32->bf16 inline staging), writes y (bf16) + per-block
//     column partial sums/sumsq to ws.
// K2: reduces partials -> scale/shift, normalize + SiLU -> fp32 out.

typedef __attribute__((ext_vector_type(8))) __bf16 bf16x8;
typedef __attribute__((ext_vector_type(4))) __bf16 bf16x4;
typedef __attribute__((ext_vector_type(4))) float  f32x4;

#define B_SZ   512
#define N_IN   64
#define D_IN   128
#define N_O    64
#define D_O    128
#define FEAT   (N_O * D_O)     // 8192
#define LDA    40              // LDS row stride (bf16 elems): 80B, 16B-aligned

__global__ __launch_bounds__(256, 2)
void gemm_stats_kernel(const float* __restrict__ x, const float* __restrict__ W,
                       const float* __restrict__ bias, const int* __restrict__ idxp,
                       __bf16* __restrict__ y, float* __restrict__ psum,
                       float* __restrict__ psq)
{
    // A tile: xg rows [128 b][32 c], k-major.  B tile: W^T [128 e][32 c], k-major.
    __shared__ __bf16 Alds[128 * LDA];
    __shared__ __bf16 Blds[128 * LDA];

    const int bx   = blockIdx.x;
    const int o    = bx >> 2;       // output group
    const int bt   = bx & 3;        // batch tile
    const int b0   = bt * 128;
    const int tid  = threadIdx.x;
    const int wave = tid >> 6;
    const int lane = tid & 63;
    const int wr   = wave >> 1;     // wave m-group (rows 64*wr..)
    const int wc   = wave & 1;      // wave n-group (cols 64*wc..)
    const int lam  = lane & 15;
    const int quad = lane >> 4;

    int rsel[4];
#pragma unroll
    for (int k = 0; k < 4; ++k) rsel[k] = idxp[o * 4 + k];

    const f32x4 zero4 = {0.f, 0.f, 0.f, 0.f};
    f32x4 acc[4][4];
#pragma unroll
    for (int mi = 0; mi < 4; ++mi)
#pragma unroll
        for (int ni = 0; ni < 4; ++ni) acc[mi][ni] = zero4;

    // A staging map: 2 threads per row, 16 floats each
    const int m_a = tid >> 1;
    const int ca  = (tid & 1) * 16;

    for (int kk = 0; kk < 16; ++kk) {
        const int kidx = kk >> 2;          // which gathered row
        const int d0   = (kk & 3) * 32;    // d-chunk within that row
        const int r    = rsel[kidx];

        // ---- global loads + cvt into registers (before barrier) ----
        const float* xa = x + (((b0 + m_a) * N_IN + r) * D_IN + d0 + ca);
        f32x4 xv0 = *(const f32x4*)(xa + 0);
        f32x4 xv1 = *(const f32x4*)(xa + 4);
        f32x4 xv2 = *(const f32x4*)(xa + 8);
        f32x4 xv3 = *(const f32x4*)(xa + 12);
        bf16x8 p0, p1;
        p0[0] = (__bf16)xv0[0]; p0[1] = (__bf16)xv0[1];
        p0[2] = (__bf16)xv0[2]; p0[3] = (__bf16)xv0[3];
        p0[4] = (__bf16)xv1[0]; p0[5] = (__bf16)xv1[1];
        p0[6] = (__bf16)xv1[2]; p0[7] = (__bf16)xv1[3];
        p1[0] = (__bf16)xv2[0]; p1[1] = (__bf16)xv2[1];
        p1[2] = (__bf16)xv2[2]; p1[3] = (__bf16)xv2[3];
        p1[4] = (__bf16)xv3[0]; p1[5] = (__bf16)xv3[1];
        p1[6] = (__bf16)xv3[2]; p1[7] = (__bf16)xv3[3];

        // B: 4 tasks/thread; each task: 4 strided-d scalar loads (coalesced
        // across lanes in e), packed to bf16x4 for a k-contiguous LDS write.
        bf16x4 wb[4];
        int te[4], tdg[4];
#pragma unroll
        for (int it = 0; it < 4; ++it) {
            const int task = it * 256 + tid;
            const int e  = task & 127;
            const int dg = task >> 7;
            te[it] = e; tdg[it] = dg;
            const float* wp = W + (((o * 4 + kidx) * 128 + (d0 + dg * 4)) * 128 + e);
            wb[it][0] = (__bf16)wp[0];
            wb[it][1] = (__bf16)wp[128];
            wb[it][2] = (__bf16)wp[256];
            wb[it][3] = (__bf16)wp[384];
        }

        __syncthreads();   // previous iteration's MFMA reads done
        *(bf16x8*)&Alds[m_a * LDA + ca]     = p0;
        *(bf16x8*)&Alds[m_a * LDA + ca + 8] = p1;
#pragma unroll
        for (int it = 0; it < 4; ++it)
            *(bf16x4*)&Blds[te[it] * LDA + tdg[it] * 4] = wb[it];
        __syncthreads();

        // ---- MFMA: A[m=lam][k=quad*8+j], B[k=quad*8+j][n=lam] ----
        bf16x8 af[4], bfv[4];
#pragma unroll
        for (int mi = 0; mi < 4; ++mi)
            af[mi] = *(const bf16x8*)&Alds[(wr * 64 + mi * 16 + lam) * LDA + quad * 8];
#pragma unroll
        for (int ni = 0; ni < 4; ++ni)
            bfv[ni] = *(const bf16x8*)&Blds[(wc * 64 + ni * 16 + lam) * LDA + quad * 8];
#pragma unroll
        for (int mi = 0; mi < 4; ++mi)
#pragma unroll
            for (int ni = 0; ni < 4; ++ni)
                acc[mi][ni] = __builtin_amdgcn_mfma_f32_16x16x32_bf16(
                    af[mi], bfv[ni], acc[mi][ni], 0, 0, 0);
    }

    // ---- epilogue: bias, y store (bf16), column partial stats ----
    const int nbase = wc * 64;
    float bvals[4];
#pragma unroll
    for (int ni = 0; ni < 4; ++ni)
        bvals[ni] = bias[o * 128 + nbase + ni * 16 + lam];

#pragma unroll
    for (int mi = 0; mi < 4; ++mi)
#pragma unroll
        for (int ni = 0; ni < 4; ++ni)
#pragma unroll
            for (int rr = 0; rr < 4; ++rr) acc[mi][ni][rr] += bvals[ni];

    // y store: D[row=quad*4+rr][col=lam]
#pragma unroll
    for (int mi = 0; mi < 4; ++mi) {
        const int mrow = b0 + wr * 64 + mi * 16 + quad * 4;
#pragma unroll
        for (int ni = 0; ni < 4; ++ni) {
            const int col = o * 128 + nbase + ni * 16 + lam;
#pragma unroll
            for (int rr = 0; rr < 4; ++rr)
                y[(mrow + rr) * FEAT + col] = (__bf16)acc[mi][ni][rr];
        }
    }

    // column partials over this wave's 64 rows (fp32, pre-rounding)
#pragma unroll
    for (int ni = 0; ni < 4; ++ni) {
        float s = 0.f, q = 0.f;
#pragma unroll
        for (int mi = 0; mi < 4; ++mi)
#pragma unroll
            for (int rr = 0; rr < 4; ++rr) {
                const float v = acc[mi][ni][rr];
                s += v; q += v * v;
            }
        s += __shfl_xor(s, 16); s += __shfl_xor(s, 32);
        q += __shfl_xor(q, 16); q += __shfl_xor(q, 32);
        if (quad == 0) {
            const int slot = bt * 2 + wr;          // 8 slots per o
            const int e    = nbase + ni * 16 + lam;
            psum[(o * 8 + slot) * 128 + e] = s;
            psq [(o * 8 + slot) * 128 + e] = q;
        }
    }
}

__global__ __launch_bounds__(256, 4)
void norm_silu_kernel(const __bf16* __restrict__ y, const float* __restrict__ psum,
                      const float* __restrict__ psq, const float* __restrict__ gamma,
                      const float* __restrict__ beta, float* __restrict__ out)
{
    __shared__ float sscale[128];
    __shared__ float sshift[128];
    const int o   = blockIdx.x >> 3;
    const int bc  = blockIdx.x & 7;   // 64-batch chunk
    const int tid = threadIdx.x;

    if (tid < 128) {
        float s = 0.f, q = 0.f;
#pragma unroll
        for (int sl = 0; sl < 8; ++sl) {
            s += psum[(o * 8 + sl) * 128 + tid];
            q += psq [(o * 8 + sl) * 128 + tid];
        }
        const float mean = s * (1.0f / 512.0f);
        const float var  = q * (1.0f / 512.0f) - mean * mean;
        const float rstd = rsqrtf(var + 1e-5f);
        const float sc   = rstd * gamma[o * 128 + tid];
        sscale[tid] = sc;
        sshift[tid] = beta[o * 128 + tid] - mean * sc;
    }
    __syncthreads();

#pragma unroll
    for (int it = 0; it < 8; ++it) {
        const int lin = it * 1024 + tid * 4;
        const int bl  = lin >> 7;
        const int e   = lin & 127;
        const int g   = (bc * 64 + bl) * FEAT + o * 128 + e;
        bf16x4 y4 = *(const bf16x4*)&y[g];
        f32x4 ov;
#pragma unroll
        for (int j = 0; j < 4; ++j) {
            const float v  = (float)y4[j];
            const float xn = v * sscale[e + j] + sshift[e + j];
            const float sg = 1.0f / (1.0f + __expf(-xn));
            ov[j] = xn * sg;
        }
        *(f32x4*)&out[g] = ov;
    }
}

extern "C" void kernel_launch(void* const* d_in, const int* in_sizes, int n_in,
                              void* d_out, int out_size, void* d_ws, size_t ws_size,
                              hipStream_t stream)
{
    const float* x     = (const float*)d_in[0];
    const float* W     = (const float*)d_in[1];
    const float* bias  = (const float*)d_in[2];
    const float* gamma = (const float*)d_in[3];
    const float* beta  = (const float*)d_in[4];
    const int*   idx   = (const int*)d_in[5];
    float* out = (float*)d_out;

    // ws layout: y bf16 (8 MiB) | psum (256 KiB) | psq (256 KiB)
    __bf16* y   = (__bf16*)d_ws;
    float* psum = (float*)((char*)d_ws + (size_t)B_SZ * FEAT * sizeof(__bf16));
    float* psq  = psum + 64 * 8 * 128;

    gemm_stats_kernel<<<dim3(256), dim3(256), 0, stream>>>(x, W, bias, idx, y, psum, psq);
    norm_silu_kernel<<<dim3(512), dim3(256), 0, stream>>>(y, psum, psq, gamma, beta, out);
}